// Round 1
// baseline (277.171 us; speedup 1.0000x reference)
//
#include <hip/hip_runtime.h>

#define N_NODES 50000
#define D 128

// ---------------- utility: zero ints ----------------
__global__ void zero_ints(int* __restrict__ p, int n) {
    int i = blockIdx.x * 256 + threadIdx.x;
    if (i < n) p[i] = 0;
}

// ---------------- histogram of dst degrees ----------------
__global__ void hist_kernel(const int* __restrict__ dst, int* __restrict__ deg, int E) {
    int e = blockIdx.x * 256 + threadIdx.x;
    if (e < E) atomicAdd(&deg[dst[e]], 1);
}

// ---------------- single-block exclusive scan over 50000 ints ----------------
__global__ __launch_bounds__(1024) void scan_kernel(const int* __restrict__ deg,
                                                    int* __restrict__ offsets) {
    __shared__ int wsum[16];
    __shared__ int carry_s;
    int t = threadIdx.x;            // 0..1023
    int lane = t & 63;
    int wid = t >> 6;               // 0..15
    if (t == 0) carry_s = 0;
    for (int base = 0; base < N_NODES; base += 1024) {
        int i = base + t;
        int v = (i < N_NODES) ? deg[i] : 0;
        // inclusive wave scan (wave64)
        int s = v;
        #pragma unroll
        for (int off = 1; off < 64; off <<= 1) {
            int u = __shfl_up(s, off);
            if (lane >= off) s += u;
        }
        if (lane == 63) wsum[wid] = s;
        __syncthreads();
        if (t == 0) {
            int c = carry_s;
            #pragma unroll
            for (int w = 0; w < 16; ++w) { int tmp = wsum[w]; wsum[w] = c; c += tmp; }
            carry_s = c;
        }
        __syncthreads();
        int excl = wsum[wid] + s - v;
        if (i < N_NODES) offsets[i] = excl;
        __syncthreads();   // protect wsum before next chunk's writes
    }
    if (t == 0) offsets[N_NODES] = carry_s;
}

// ---------------- scatter edges into CSR order ----------------
__global__ void scatter_kernel(const int* __restrict__ src, const int* __restrict__ dst,
                               const int* __restrict__ offsets, int* __restrict__ cursor,
                               int* __restrict__ sorted_src, int E) {
    int e = blockIdx.x * 256 + threadIdx.x;
    if (e < E) {
        int d = dst[e];
        int pos = offsets[d] + atomicAdd(&cursor[d], 1);
        sorted_src[pos] = src[e];
    }
}

// ---------------- per-node mean aggregation ----------------
// one block (128 threads) per node; thread j owns feature j
__global__ __launch_bounds__(128) void aggregate_kernel(const float* __restrict__ x,
                                                        const int* __restrict__ sorted_src,
                                                        const int* __restrict__ offsets,
                                                        float* __restrict__ agg) {
    int node = blockIdx.x;
    int j = threadIdx.x;
    int s = offsets[node];
    int e = offsets[node + 1];
    float sum = 0.0f;
    for (int p = s; p < e; ++p) {
        int srcn = sorted_src[p];
        sum += x[srcn * D + j];
    }
    int d = e - s;
    float scale = (d > 0) ? (1.0f / (float)d) : 0.0f;
    agg[node * D + j] = sum * scale;
}

// ---------------- fused dual GEMM + bias + relu ----------------
// out[n][:] = relu(agg[n] @ Wl + x[n] @ Wr + b)
// 64 nodes per block, 256 threads, per-thread 8 nodes x 4 cols.
// NOTE: agg may alias out (each block reads only its own 64 rows, writes them last).
__global__ __launch_bounds__(256) void gemm_fused(const float* __restrict__ agg,
                                                  const float* __restrict__ x,
                                                  const float* __restrict__ Wl,
                                                  const float* __restrict__ Wr,
                                                  const float* __restrict__ bias,
                                                  float* __restrict__ out) {
    __shared__ float As[64][32];
    __shared__ float Xs[64][32];
    __shared__ float Wls[32][128];
    __shared__ float Wrs[32][128];

    const int n0 = blockIdx.x * 64;
    const int t = threadIdx.x;
    const int cg = t & 31;          // col group
    const int col0 = cg * 4;
    const int ng = t >> 5;          // node group 0..7

    float acc[8][4];
    #pragma unroll
    for (int r = 0; r < 8; ++r)
        #pragma unroll
        for (int c = 0; c < 4; ++c) acc[r][c] = 0.0f;

    for (int k0 = 0; k0 < D; k0 += 32) {
        __syncthreads();
        // stage W chunks: 32 rows x 128 cols each
        #pragma unroll
        for (int i = 0; i < 4; ++i) {
            int fid = t + i * 256;          // 0..1023
            int row = fid >> 5;             // 0..31
            int c4 = fid & 31;
            *(float4*)&Wls[row][c4 * 4] = *(const float4*)&Wl[(k0 + row) * D + c4 * 4];
            *(float4*)&Wrs[row][c4 * 4] = *(const float4*)&Wr[(k0 + row) * D + c4 * 4];
        }
        // stage A and X chunks: 64 rows x 32 cols
        #pragma unroll
        for (int i = 0; i < 2; ++i) {
            int fid = t + i * 256;          // 0..511
            int row = fid >> 3;             // 0..63
            int m = fid & 7;                // float4 index within 32 cols
            int n = n0 + row;
            int nn = (n < N_NODES) ? n : (N_NODES - 1);
            *(float4*)&As[row][m * 4] = *(const float4*)&agg[nn * D + k0 + m * 4];
            *(float4*)&Xs[row][m * 4] = *(const float4*)&x[nn * D + k0 + m * 4];
        }
        __syncthreads();

        for (int kk = 0; kk < 32; ++kk) {
            const float4 wl = *(const float4*)&Wls[kk][col0];
            const float4 wr = *(const float4*)&Wrs[kk][col0];
            #pragma unroll
            for (int r = 0; r < 8; ++r) {
                float a  = As[ng * 8 + r][kk];
                float xx = Xs[ng * 8 + r][kk];
                acc[r][0] = fmaf(a, wl.x, fmaf(xx, wr.x, acc[r][0]));
                acc[r][1] = fmaf(a, wl.y, fmaf(xx, wr.y, acc[r][1]));
                acc[r][2] = fmaf(a, wl.z, fmaf(xx, wr.z, acc[r][2]));
                acc[r][3] = fmaf(a, wl.w, fmaf(xx, wr.w, acc[r][3]));
            }
        }
    }

    const float4 bb = *(const float4*)&bias[col0];
    #pragma unroll
    for (int r = 0; r < 8; ++r) {
        int n = n0 + ng * 8 + r;
        if (n < N_NODES) {
            float4 o;
            o.x = fmaxf(acc[r][0] + bb.x, 0.0f);
            o.y = fmaxf(acc[r][1] + bb.y, 0.0f);
            o.z = fmaxf(acc[r][2] + bb.z, 0.0f);
            o.w = fmaxf(acc[r][3] + bb.w, 0.0f);
            *(float4*)&out[n * D + col0] = o;
        }
    }
}

extern "C" void kernel_launch(void* const* d_in, const int* in_sizes, int n_in,
                              void* d_out, int out_size, void* d_ws, size_t ws_size,
                              hipStream_t stream) {
    const float* x  = (const float*)d_in[0];
    const int*   ei = (const int*)d_in[1];
    const float* Wl = (const float*)d_in[2];
    const float* Wr = (const float*)d_in[3];
    const float* b  = (const float*)d_in[4];
    float* out = (float*)d_out;

    const int E = in_sizes[1] / 2;
    const int* src = ei;
    const int* dst = ei + E;

    // workspace layout (ints)
    int* deg     = (int*)d_ws;           // 50016
    int* cursor  = deg + 50016;          // 50016
    int* offsets = cursor + 50016;       // 50016 (uses 50001)
    int* sorted  = offsets + 50016;      // 800000
    float* agg   = out;                  // reuse d_out as agg buffer (safe: see gemm_fused)

    zero_ints<<<(100032 + 255) / 256, 256, 0, stream>>>(deg, 100032);
    hist_kernel<<<(E + 255) / 256, 256, 0, stream>>>(dst, deg, E);
    scan_kernel<<<1, 1024, 0, stream>>>(deg, offsets);
    scatter_kernel<<<(E + 255) / 256, 256, 0, stream>>>(src, dst, offsets, cursor, sorted, E);
    aggregate_kernel<<<N_NODES, 128, 0, stream>>>(x, sorted, offsets, agg);
    gemm_fused<<<(N_NODES + 63) / 64, 256, 0, stream>>>(agg, x, Wl, Wr, b, out);
}

// Round 2
// 206.723 us; speedup vs baseline: 1.3408x; 1.3408x over previous
//
#include <hip/hip_runtime.h>

#define N_NODES 50000
#define D 128
#define SCAN_NBLK 49   // ceil(50000/1024)

// ---------------- utility: zero ints ----------------
__global__ void zero_ints(int* __restrict__ p, int n) {
    int i = blockIdx.x * 256 + threadIdx.x;
    if (i < n) p[i] = 0;
}

// ---------------- histogram of dst degrees ----------------
__global__ void hist_kernel(const int* __restrict__ dst, int* __restrict__ deg, int E) {
    int e = blockIdx.x * 256 + threadIdx.x;
    if (e < E) atomicAdd(&deg[dst[e]], 1);
}

// ---------------- hierarchical scan: phase A (per-block local exclusive scan) ----
// 256 threads x 4 elems = 1024 elems/block
__global__ __launch_bounds__(256) void scanA_kernel(const int* __restrict__ deg,
                                                    int* __restrict__ offsets,
                                                    int* __restrict__ blocksums) {
    __shared__ int wsums[4];
    __shared__ int wbase[4];
    const int t = threadIdx.x;
    const int lane = t & 63;
    const int wid = t >> 6;
    const int base = blockIdx.x * 1024 + t * 4;

    int v0 = 0, v1 = 0, v2 = 0, v3 = 0;
    if (base + 3 < N_NODES) {
        int4 q = *(const int4*)&deg[base];
        v0 = q.x; v1 = q.y; v2 = q.z; v3 = q.w;
    } else {
        if (base + 0 < N_NODES) v0 = deg[base + 0];
        if (base + 1 < N_NODES) v1 = deg[base + 1];
        if (base + 2 < N_NODES) v2 = deg[base + 2];
        if (base + 3 < N_NODES) v3 = deg[base + 3];
    }
    int tsum = v0 + v1 + v2 + v3;

    // inclusive wave scan of per-thread sums
    int sc = tsum;
    #pragma unroll
    for (int off = 1; off < 64; off <<= 1) {
        int u = __shfl_up(sc, off);
        if (lane >= off) sc += u;
    }
    if (lane == 63) wsums[wid] = sc;
    __syncthreads();
    if (t == 0) {
        int c = 0;
        #pragma unroll
        for (int w = 0; w < 4; ++w) { wbase[w] = c; c += wsums[w]; }
    }
    __syncthreads();

    int excl = wbase[wid] + sc - tsum;   // exclusive prefix of this thread in block
    int o0 = excl, o1 = o0 + v0, o2 = o1 + v1, o3 = o2 + v2;
    if (base + 3 < N_NODES) {
        *(int4*)&offsets[base] = make_int4(o0, o1, o2, o3);
    } else {
        if (base + 0 < N_NODES) offsets[base + 0] = o0;
        if (base + 1 < N_NODES) offsets[base + 1] = o1;
        if (base + 2 < N_NODES) offsets[base + 2] = o2;
        if (base + 3 < N_NODES) offsets[base + 3] = o3;
    }
    if (t == 255) blocksums[blockIdx.x] = excl + tsum;   // block total
}

// ---------------- phase B: scan the 49 block sums (one wave) ----------------
__global__ __launch_bounds__(64) void scanB_kernel(const int* __restrict__ blocksums,
                                                   int* __restrict__ blockbase,
                                                   int* __restrict__ offsets, int E) {
    int t = threadIdx.x;   // 0..63
    int v = (t < SCAN_NBLK) ? blocksums[t] : 0;
    int sc = v;
    #pragma unroll
    for (int off = 1; off < 64; off <<= 1) {
        int u = __shfl_up(sc, off);
        if (t >= off) sc += u;
    }
    if (t < SCAN_NBLK) blockbase[t] = sc - v;
    if (t == 0) offsets[N_NODES] = E;
}

// ---------------- phase C: add block bases ----------------
__global__ __launch_bounds__(256) void scanC_kernel(int* __restrict__ offsets,
                                                    const int* __restrict__ blockbase) {
    int b = blockIdx.x;
    int add = blockbase[b];
    if (add == 0) return;
    int base = b * 1024 + threadIdx.x * 4;
    if (base + 3 < N_NODES) {
        int4 q = *(int4*)&offsets[base];
        q.x += add; q.y += add; q.z += add; q.w += add;
        *(int4*)&offsets[base] = q;
    } else {
        if (base + 0 < N_NODES) offsets[base + 0] += add;
        if (base + 1 < N_NODES) offsets[base + 1] += add;
        if (base + 2 < N_NODES) offsets[base + 2] += add;
        if (base + 3 < N_NODES) offsets[base + 3] += add;
    }
}

// ---------------- scatter edges into CSR order ----------------
__global__ void scatter_kernel(const int* __restrict__ src, const int* __restrict__ dst,
                               const int* __restrict__ offsets, int* __restrict__ cursor,
                               int* __restrict__ sorted_src, int E) {
    int e = blockIdx.x * 256 + threadIdx.x;
    if (e < E) {
        int d = dst[e];
        int pos = offsets[d] + atomicAdd(&cursor[d], 1);
        sorted_src[pos] = src[e];
    }
}

// ---------------- per-node mean aggregation ----------------
// 32 lanes per node (float4 each), 8 nodes per 256-thread block, 2-edge unroll
__global__ __launch_bounds__(256) void aggregate_kernel(const float* __restrict__ x,
                                                        const int* __restrict__ sorted_src,
                                                        const int* __restrict__ offsets,
                                                        float* __restrict__ agg) {
    const int g = threadIdx.x >> 5;          // node group 0..7
    const int j = threadIdx.x & 31;          // float4 slot 0..31
    const int node = blockIdx.x * 8 + g;
    if (node >= N_NODES) return;
    const int s = offsets[node];
    const int e = offsets[node + 1];

    float4 a0 = make_float4(0.f, 0.f, 0.f, 0.f);
    float4 a1 = make_float4(0.f, 0.f, 0.f, 0.f);
    int p = s;
    for (; p + 2 <= e; p += 2) {
        int s0 = sorted_src[p];
        int s1 = sorted_src[p + 1];
        float4 r0 = *(const float4*)&x[s0 * D + j * 4];
        float4 r1 = *(const float4*)&x[s1 * D + j * 4];
        a0.x += r0.x; a0.y += r0.y; a0.z += r0.z; a0.w += r0.w;
        a1.x += r1.x; a1.y += r1.y; a1.z += r1.z; a1.w += r1.w;
    }
    if (p < e) {
        int s0 = sorted_src[p];
        float4 r0 = *(const float4*)&x[s0 * D + j * 4];
        a0.x += r0.x; a0.y += r0.y; a0.z += r0.z; a0.w += r0.w;
    }
    const int d = e - s;
    const float sc = (d > 0) ? (1.0f / (float)d) : 0.0f;
    float4 o;
    o.x = (a0.x + a1.x) * sc;
    o.y = (a0.y + a1.y) * sc;
    o.z = (a0.z + a1.z) * sc;
    o.w = (a0.w + a1.w) * sc;
    *(float4*)&agg[node * D + j * 4] = o;
}

// ---------------- fused dual GEMM + bias + relu ----------------
// out[n][:] = relu(agg[n] @ Wl + x[n] @ Wr + b)
// 64 nodes per block, 256 threads, per-thread 8 nodes x 4 cols.
// NOTE: agg aliases out (each block reads only its own 64 rows, writes them last).
__global__ __launch_bounds__(256) void gemm_fused(const float* __restrict__ agg,
                                                  const float* __restrict__ x,
                                                  const float* __restrict__ Wl,
                                                  const float* __restrict__ Wr,
                                                  const float* __restrict__ bias,
                                                  float* __restrict__ out) {
    __shared__ float As[64][32];
    __shared__ float Xs[64][32];
    __shared__ float Wls[32][128];
    __shared__ float Wrs[32][128];

    const int n0 = blockIdx.x * 64;
    const int t = threadIdx.x;
    const int cg = t & 31;          // col group
    const int col0 = cg * 4;
    const int ng = t >> 5;          // node group 0..7

    float acc[8][4];
    #pragma unroll
    for (int r = 0; r < 8; ++r)
        #pragma unroll
        for (int c = 0; c < 4; ++c) acc[r][c] = 0.0f;

    for (int k0 = 0; k0 < D; k0 += 32) {
        __syncthreads();
        #pragma unroll
        for (int i = 0; i < 4; ++i) {
            int fid = t + i * 256;          // 0..1023
            int row = fid >> 5;             // 0..31
            int c4 = fid & 31;
            *(float4*)&Wls[row][c4 * 4] = *(const float4*)&Wl[(k0 + row) * D + c4 * 4];
            *(float4*)&Wrs[row][c4 * 4] = *(const float4*)&Wr[(k0 + row) * D + c4 * 4];
        }
        #pragma unroll
        for (int i = 0; i < 2; ++i) {
            int fid = t + i * 256;          // 0..511
            int row = fid >> 3;             // 0..63
            int m = fid & 7;                // float4 index within 32 cols
            int n = n0 + row;
            int nn = (n < N_NODES) ? n : (N_NODES - 1);
            *(float4*)&As[row][m * 4] = *(const float4*)&agg[nn * D + k0 + m * 4];
            *(float4*)&Xs[row][m * 4] = *(const float4*)&x[nn * D + k0 + m * 4];
        }
        __syncthreads();

        for (int kk = 0; kk < 32; ++kk) {
            const float4 wl = *(const float4*)&Wls[kk][col0];
            const float4 wr = *(const float4*)&Wrs[kk][col0];
            #pragma unroll
            for (int r = 0; r < 8; ++r) {
                float a  = As[ng * 8 + r][kk];
                float xx = Xs[ng * 8 + r][kk];
                acc[r][0] = fmaf(a, wl.x, fmaf(xx, wr.x, acc[r][0]));
                acc[r][1] = fmaf(a, wl.y, fmaf(xx, wr.y, acc[r][1]));
                acc[r][2] = fmaf(a, wl.z, fmaf(xx, wr.z, acc[r][2]));
                acc[r][3] = fmaf(a, wl.w, fmaf(xx, wr.w, acc[r][3]));
            }
        }
    }

    const float4 bb = *(const float4*)&bias[col0];
    #pragma unroll
    for (int r = 0; r < 8; ++r) {
        int n = n0 + ng * 8 + r;
        if (n < N_NODES) {
            float4 o;
            o.x = fmaxf(acc[r][0] + bb.x, 0.0f);
            o.y = fmaxf(acc[r][1] + bb.y, 0.0f);
            o.z = fmaxf(acc[r][2] + bb.z, 0.0f);
            o.w = fmaxf(acc[r][3] + bb.w, 0.0f);
            *(float4*)&out[n * D + col0] = o;
        }
    }
}

extern "C" void kernel_launch(void* const* d_in, const int* in_sizes, int n_in,
                              void* d_out, int out_size, void* d_ws, size_t ws_size,
                              hipStream_t stream) {
    const float* x  = (const float*)d_in[0];
    const int*   ei = (const int*)d_in[1];
    const float* Wl = (const float*)d_in[2];
    const float* Wr = (const float*)d_in[3];
    const float* b  = (const float*)d_in[4];
    float* out = (float*)d_out;

    const int E = in_sizes[1] / 2;
    const int* src = ei;
    const int* dst = ei + E;

    // workspace layout (ints)
    int* deg       = (int*)d_ws;           // 50016
    int* cursor    = deg + 50016;          // 50016
    int* offsets   = cursor + 50016;       // 50016 (uses 50001)
    int* sorted    = offsets + 50016;      // 800000
    int* blocksums = sorted + 800000;      // 64
    int* blockbase = blocksums + 64;       // 64
    float* agg     = out;                  // reuse d_out as agg buffer

    zero_ints<<<(100032 + 255) / 256, 256, 0, stream>>>(deg, 100032);
    hist_kernel<<<(E + 255) / 256, 256, 0, stream>>>(dst, deg, E);
    scanA_kernel<<<SCAN_NBLK, 256, 0, stream>>>(deg, offsets, blocksums);
    scanB_kernel<<<1, 64, 0, stream>>>(blocksums, blockbase, offsets, E);
    scanC_kernel<<<SCAN_NBLK, 256, 0, stream>>>(offsets, blockbase);
    scatter_kernel<<<(E + 255) / 256, 256, 0, stream>>>(src, dst, offsets, cursor, sorted, E);
    aggregate_kernel<<<(N_NODES + 7) / 8, 256, 0, stream>>>(x, sorted, offsets, agg);
    gemm_fused<<<(N_NODES + 63) / 64, 256, 0, stream>>>(agg, x, Wl, Wr, b, out);
}

// Round 3
// 150.964 us; speedup vs baseline: 1.8360x; 1.3694x over previous
//
#include <hip/hip_runtime.h>

#define N_NODES 50000
#define D 128
#define SCAN_NBLK 49   // ceil(50000/1024)

typedef short bf16x8 __attribute__((ext_vector_type(8)));
typedef float f32x4 __attribute__((ext_vector_type(4)));

__device__ __forceinline__ ushort f2bf(float f) {
    uint u = __float_as_uint(f);
    u += 0x7FFF + ((u >> 16) & 1);     // round-to-nearest-even
    return (ushort)(u >> 16);
}

// ================= prep: zero counters + x->bf16 + W transpose->bf16 ========
__global__ __launch_bounds__(256) void prep_kernel(const float* __restrict__ x,
                                                   const float* __restrict__ Wl,
                                                   const float* __restrict__ Wr,
                                                   int* __restrict__ zero_region,
                                                   ushort* __restrict__ x_bf,
                                                   ushort* __restrict__ Bt) {
    int i = blockIdx.x * 256 + threadIdx.x;
    // x -> bf16, float4 granularity (1,600,000 float4s)
    if (i < (N_NODES * D) / 4) {
        float4 v = ((const float4*)x)[i];
        ushort4 o;
        o.x = f2bf(v.x); o.y = f2bf(v.y); o.z = f2bf(v.z); o.w = f2bf(v.w);
        ((ushort4*)x_bf)[i] = o;
    }
    // zero deg+cursor
    if (i < 100032) zero_region[i] = 0;
    // W transpose: Bt[w][n][k] = bf16(W_w[k][n]); 2*128*128 = 32768 elems
    if (i < 2 * D * D) {
        int w = i >> 14;
        int k = (i >> 7) & 127;
        int n = i & 127;
        const float* W = w ? Wr : Wl;
        Bt[w * D * D + n * D + k] = f2bf(W[k * D + n]);
    }
}

// ---------------- histogram of dst degrees ----------------
__global__ void hist_kernel(const int* __restrict__ dst, int* __restrict__ deg, int E) {
    int e = blockIdx.x * 256 + threadIdx.x;
    if (e < E) atomicAdd(&deg[dst[e]], 1);
}

// ---------------- hierarchical scan ----------------
__global__ __launch_bounds__(256) void scanA_kernel(const int* __restrict__ deg,
                                                    int* __restrict__ offsets,
                                                    int* __restrict__ blocksums) {
    __shared__ int wsums[4];
    __shared__ int wbase[4];
    const int t = threadIdx.x;
    const int lane = t & 63;
    const int wid = t >> 6;
    const int base = blockIdx.x * 1024 + t * 4;

    int v0 = 0, v1 = 0, v2 = 0, v3 = 0;
    if (base + 3 < N_NODES) {
        int4 q = *(const int4*)&deg[base];
        v0 = q.x; v1 = q.y; v2 = q.z; v3 = q.w;
    } else {
        if (base + 0 < N_NODES) v0 = deg[base + 0];
        if (base + 1 < N_NODES) v1 = deg[base + 1];
        if (base + 2 < N_NODES) v2 = deg[base + 2];
        if (base + 3 < N_NODES) v3 = deg[base + 3];
    }
    int tsum = v0 + v1 + v2 + v3;

    int sc = tsum;
    #pragma unroll
    for (int off = 1; off < 64; off <<= 1) {
        int u = __shfl_up(sc, off);
        if (lane >= off) sc += u;
    }
    if (lane == 63) wsums[wid] = sc;
    __syncthreads();
    if (t == 0) {
        int c = 0;
        #pragma unroll
        for (int w = 0; w < 4; ++w) { wbase[w] = c; c += wsums[w]; }
    }
    __syncthreads();

    int excl = wbase[wid] + sc - tsum;
    int o0 = excl, o1 = o0 + v0, o2 = o1 + v1, o3 = o2 + v2;
    if (base + 3 < N_NODES) {
        *(int4*)&offsets[base] = make_int4(o0, o1, o2, o3);
    } else {
        if (base + 0 < N_NODES) offsets[base + 0] = o0;
        if (base + 1 < N_NODES) offsets[base + 1] = o1;
        if (base + 2 < N_NODES) offsets[base + 2] = o2;
        if (base + 3 < N_NODES) offsets[base + 3] = o3;
    }
    if (t == 255) blocksums[blockIdx.x] = excl + tsum;
}

__global__ __launch_bounds__(64) void scanB_kernel(const int* __restrict__ blocksums,
                                                   int* __restrict__ blockbase,
                                                   int* __restrict__ offsets, int E) {
    int t = threadIdx.x;
    int v = (t < SCAN_NBLK) ? blocksums[t] : 0;
    int sc = v;
    #pragma unroll
    for (int off = 1; off < 64; off <<= 1) {
        int u = __shfl_up(sc, off);
        if (t >= off) sc += u;
    }
    if (t < SCAN_NBLK) blockbase[t] = sc - v;
    if (t == 0) offsets[N_NODES] = E;
}

__global__ __launch_bounds__(256) void scanC_kernel(int* __restrict__ offsets,
                                                    const int* __restrict__ blockbase) {
    int b = blockIdx.x;
    int add = blockbase[b];
    if (add == 0) return;
    int base = b * 1024 + threadIdx.x * 4;
    if (base + 3 < N_NODES) {
        int4 q = *(int4*)&offsets[base];
        q.x += add; q.y += add; q.z += add; q.w += add;
        *(int4*)&offsets[base] = q;
    } else {
        if (base + 0 < N_NODES) offsets[base + 0] += add;
        if (base + 1 < N_NODES) offsets[base + 1] += add;
        if (base + 2 < N_NODES) offsets[base + 2] += add;
    }
}

// ---------------- scatter edges into CSR order ----------------
__global__ void scatter_kernel(const int* __restrict__ src, const int* __restrict__ dst,
                               const int* __restrict__ offsets, int* __restrict__ cursor,
                               int* __restrict__ sorted_src, int E) {
    int e = blockIdx.x * 256 + threadIdx.x;
    if (e < E) {
        int d = dst[e];
        int pos = offsets[d] + atomicAdd(&cursor[d], 1);
        sorted_src[pos] = src[e];
    }
}

// ---------------- per-node mean aggregation (bf16 gather) ----------------
// 32 lanes per node (uint2 = 4 bf16 each), 8 nodes per 256-thread block
__global__ __launch_bounds__(256) void aggregate_bf(const ushort* __restrict__ x_bf,
                                                    const int* __restrict__ sorted_src,
                                                    const int* __restrict__ offsets,
                                                    float* __restrict__ agg) {
    const int g = threadIdx.x >> 5;
    const int j = threadIdx.x & 31;
    const int node = blockIdx.x * 8 + g;
    if (node >= N_NODES) return;
    const int s = offsets[node];
    const int e = offsets[node + 1];

    float a0 = 0.f, a1 = 0.f, a2 = 0.f, a3 = 0.f;
    int p = s;
    for (; p + 4 <= e; p += 4) {
        int s0 = sorted_src[p], s1 = sorted_src[p + 1];
        int s2 = sorted_src[p + 2], s3 = sorted_src[p + 3];
        uint2 r0 = *(const uint2*)&x_bf[s0 * D + j * 4];
        uint2 r1 = *(const uint2*)&x_bf[s1 * D + j * 4];
        uint2 r2 = *(const uint2*)&x_bf[s2 * D + j * 4];
        uint2 r3 = *(const uint2*)&x_bf[s3 * D + j * 4];
        a0 += __uint_as_float(r0.x << 16) + __uint_as_float(r1.x << 16)
            + __uint_as_float(r2.x << 16) + __uint_as_float(r3.x << 16);
        a1 += __uint_as_float(r0.x & 0xFFFF0000u) + __uint_as_float(r1.x & 0xFFFF0000u)
            + __uint_as_float(r2.x & 0xFFFF0000u) + __uint_as_float(r3.x & 0xFFFF0000u);
        a2 += __uint_as_float(r0.y << 16) + __uint_as_float(r1.y << 16)
            + __uint_as_float(r2.y << 16) + __uint_as_float(r3.y << 16);
        a3 += __uint_as_float(r0.y & 0xFFFF0000u) + __uint_as_float(r1.y & 0xFFFF0000u)
            + __uint_as_float(r2.y & 0xFFFF0000u) + __uint_as_float(r3.y & 0xFFFF0000u);
    }
    for (; p < e; ++p) {
        int s0 = sorted_src[p];
        uint2 r0 = *(const uint2*)&x_bf[s0 * D + j * 4];
        a0 += __uint_as_float(r0.x << 16);
        a1 += __uint_as_float(r0.x & 0xFFFF0000u);
        a2 += __uint_as_float(r0.y << 16);
        a3 += __uint_as_float(r0.y & 0xFFFF0000u);
    }
    const int d = e - s;
    const float sc = (d > 0) ? (1.0f / (float)d) : 0.0f;
    float4 o = make_float4(a0 * sc, a1 * sc, a2 * sc, a3 * sc);
    *(float4*)&agg[node * D + j * 4] = o;
}

// ---------------- MFMA bf16 GEMM: out = relu([agg|x] @ [Wl;Wr] + b) ---------
// 128 rows x 128 cols per block, 4 waves (each 32 rows x 128 cols).
// agg aliases out; each block reads only its own rows before writing them.
#define LDA 40   // bf16 units per LDS row (32 data + 8 pad) -> 80B stride
__global__ __launch_bounds__(256) void gemm_mfma(const float* __restrict__ agg,
                                                 const ushort* __restrict__ x_bf,
                                                 const ushort* __restrict__ Bt,
                                                 const float* __restrict__ bias,
                                                 float* __restrict__ out) {
    __shared__ ushort A_s[128 * LDA];
    __shared__ ushort B_s[128 * LDA];

    const int t = threadIdx.x;
    const int n0 = blockIdx.x * 128;
    const int w = t >> 6;
    const int l = t & 63;
    const int lr = l & 15;        // row (A) / col (B/D) within fragment
    const int kb = l >> 4;        // k-block 0..3

    f32x4 acc[2][8] = {};

    const int srow = t >> 1;      // 0..127 staging row/col
    const int shalf = t & 1;      // which 16-element half

    for (int ks = 0; ks < 8; ++ks) {
        __syncthreads();
        // ---- stage A (rows = nodes) ----
        {
            int gr = n0 + srow;
            if (gr >= N_NODES) gr = N_NODES - 1;
            ushort tmp[16];
            if (ks < 4) {
                const float4* src = (const float4*)(agg + gr * D + ks * 32 + shalf * 16);
                #pragma unroll
                for (int i = 0; i < 4; ++i) {
                    float4 v = src[i];
                    tmp[i * 4 + 0] = f2bf(v.x);
                    tmp[i * 4 + 1] = f2bf(v.y);
                    tmp[i * 4 + 2] = f2bf(v.z);
                    tmp[i * 4 + 3] = f2bf(v.w);
                }
            } else {
                const int4* src = (const int4*)(x_bf + gr * D + (ks - 4) * 32 + shalf * 16);
                ((int4*)tmp)[0] = src[0];
                ((int4*)tmp)[1] = src[1];
            }
            ushort* d = &A_s[srow * LDA + shalf * 16];
            ((int4*)d)[0] = ((int4*)tmp)[0];
            ((int4*)d)[1] = ((int4*)tmp)[1];
        }
        // ---- stage B (cols) from pre-transposed bf16 Bt[w][n][k] ----
        {
            const int4* src = (const int4*)(Bt + (ks >> 2) * D * D + srow * D + (ks & 3) * 32 + shalf * 16);
            ushort* d = &B_s[srow * LDA + shalf * 16];
            ((int4*)d)[0] = src[0];
            ((int4*)d)[1] = src[1];
        }
        __syncthreads();

        bf16x8 af0 = *(bf16x8*)&A_s[(w * 32 + lr) * LDA + kb * 8];
        bf16x8 af1 = *(bf16x8*)&A_s[(w * 32 + 16 + lr) * LDA + kb * 8];
        #pragma unroll
        for (int nf = 0; nf < 8; ++nf) {
            bf16x8 bfr = *(bf16x8*)&B_s[(nf * 16 + lr) * LDA + kb * 8];
            acc[0][nf] = __builtin_amdgcn_mfma_f32_16x16x32_bf16(af0, bfr, acc[0][nf], 0, 0, 0);
            acc[1][nf] = __builtin_amdgcn_mfma_f32_16x16x32_bf16(af1, bfr, acc[1][nf], 0, 0, 0);
        }
    }

    // epilogue: C/D layout col = lane&15, row = (lane>>4)*4 + i
    #pragma unroll
    for (int nf = 0; nf < 8; ++nf) {
        const int col = nf * 16 + lr;
        const float bb = bias[col];
        #pragma unroll
        for (int mf = 0; mf < 2; ++mf) {
            #pragma unroll
            for (int i = 0; i < 4; ++i) {
                int row = n0 + w * 32 + mf * 16 + kb * 4 + i;
                if (row < N_NODES)
                    out[row * D + col] = fmaxf(acc[mf][nf][i] + bb, 0.0f);
            }
        }
    }
}

// ================= fallback f32 path (small ws) =============================
__global__ void zero_ints(int* __restrict__ p, int n) {
    int i = blockIdx.x * 256 + threadIdx.x;
    if (i < n) p[i] = 0;
}

__global__ __launch_bounds__(256) void aggregate_kernel(const float* __restrict__ x,
                                                        const int* __restrict__ sorted_src,
                                                        const int* __restrict__ offsets,
                                                        float* __restrict__ agg) {
    const int g = threadIdx.x >> 5;
    const int j = threadIdx.x & 31;
    const int node = blockIdx.x * 8 + g;
    if (node >= N_NODES) return;
    const int s = offsets[node];
    const int e = offsets[node + 1];
    float4 a0 = make_float4(0.f, 0.f, 0.f, 0.f);
    float4 a1 = make_float4(0.f, 0.f, 0.f, 0.f);
    int p = s;
    for (; p + 2 <= e; p += 2) {
        int s0 = sorted_src[p];
        int s1 = sorted_src[p + 1];
        float4 r0 = *(const float4*)&x[s0 * D + j * 4];
        float4 r1 = *(const float4*)&x[s1 * D + j * 4];
        a0.x += r0.x; a0.y += r0.y; a0.z += r0.z; a0.w += r0.w;
        a1.x += r1.x; a1.y += r1.y; a1.z += r1.z; a1.w += r1.w;
    }
    if (p < e) {
        int s0 = sorted_src[p];
        float4 r0 = *(const float4*)&x[s0 * D + j * 4];
        a0.x += r0.x; a0.y += r0.y; a0.z += r0.z; a0.w += r0.w;
    }
    const int d = e - s;
    const float sc = (d > 0) ? (1.0f / (float)d) : 0.0f;
    float4 o;
    o.x = (a0.x + a1.x) * sc;
    o.y = (a0.y + a1.y) * sc;
    o.z = (a0.z + a1.z) * sc;
    o.w = (a0.w + a1.w) * sc;
    *(float4*)&agg[node * D + j * 4] = o;
}

__global__ __launch_bounds__(256) void gemm_fused(const float* __restrict__ agg,
                                                  const float* __restrict__ x,
                                                  const float* __restrict__ Wl,
                                                  const float* __restrict__ Wr,
                                                  const float* __restrict__ bias,
                                                  float* __restrict__ out) {
    __shared__ float As[64][32];
    __shared__ float Xs[64][32];
    __shared__ float Wls[32][128];
    __shared__ float Wrs[32][128];

    const int n0 = blockIdx.x * 64;
    const int t = threadIdx.x;
    const int cg = t & 31;
    const int col0 = cg * 4;
    const int ng = t >> 5;

    float acc[8][4];
    #pragma unroll
    for (int r = 0; r < 8; ++r)
        #pragma unroll
        for (int c = 0; c < 4; ++c) acc[r][c] = 0.0f;

    for (int k0 = 0; k0 < D; k0 += 32) {
        __syncthreads();
        #pragma unroll
        for (int i = 0; i < 4; ++i) {
            int fid = t + i * 256;
            int row = fid >> 5;
            int c4 = fid & 31;
            *(float4*)&Wls[row][c4 * 4] = *(const float4*)&Wl[(k0 + row) * D + c4 * 4];
            *(float4*)&Wrs[row][c4 * 4] = *(const float4*)&Wr[(k0 + row) * D + c4 * 4];
        }
        #pragma unroll
        for (int i = 0; i < 2; ++i) {
            int fid = t + i * 256;
            int row = fid >> 3;
            int m = fid & 7;
            int n = n0 + row;
            int nn = (n < N_NODES) ? n : (N_NODES - 1);
            *(float4*)&As[row][m * 4] = *(const float4*)&agg[nn * D + k0 + m * 4];
            *(float4*)&Xs[row][m * 4] = *(const float4*)&x[nn * D + k0 + m * 4];
        }
        __syncthreads();

        for (int kk = 0; kk < 32; ++kk) {
            const float4 wl = *(const float4*)&Wls[kk][col0];
            const float4 wr = *(const float4*)&Wrs[kk][col0];
            #pragma unroll
            for (int r = 0; r < 8; ++r) {
                float a  = As[ng * 8 + r][kk];
                float xx = Xs[ng * 8 + r][kk];
                acc[r][0] = fmaf(a, wl.x, fmaf(xx, wr.x, acc[r][0]));
                acc[r][1] = fmaf(a, wl.y, fmaf(xx, wr.y, acc[r][1]));
                acc[r][2] = fmaf(a, wl.z, fmaf(xx, wr.z, acc[r][2]));
                acc[r][3] = fmaf(a, wl.w, fmaf(xx, wr.w, acc[r][3]));
            }
        }
    }

    const float4 bb = *(const float4*)&bias[col0];
    #pragma unroll
    for (int r = 0; r < 8; ++r) {
        int n = n0 + ng * 8 + r;
        if (n < N_NODES) {
            float4 o;
            o.x = fmaxf(acc[r][0] + bb.x, 0.0f);
            o.y = fmaxf(acc[r][1] + bb.y, 0.0f);
            o.z = fmaxf(acc[r][2] + bb.z, 0.0f);
            o.w = fmaxf(acc[r][3] + bb.w, 0.0f);
            *(float4*)&out[n * D + col0] = o;
        }
    }
}

// ============================================================================
extern "C" void kernel_launch(void* const* d_in, const int* in_sizes, int n_in,
                              void* d_out, int out_size, void* d_ws, size_t ws_size,
                              hipStream_t stream) {
    const float* x  = (const float*)d_in[0];
    const int*   ei = (const int*)d_in[1];
    const float* Wl = (const float*)d_in[2];
    const float* Wr = (const float*)d_in[3];
    const float* b  = (const float*)d_in[4];
    float* out = (float*)d_out;

    const int E = in_sizes[1] / 2;
    const int* src = ei;
    const int* dst = ei + E;

    // workspace layout (ints first)
    int* deg       = (int*)d_ws;           // 50016
    int* cursor    = deg + 50016;          // 50016
    int* offsets   = cursor + 50016;       // 50016 (uses 50001)
    int* sorted    = offsets + 50016;      // 800000
    int* blocksums = sorted + 800000;      // 64
    int* blockbase = blocksums + 64;       // 64  -> int end = 950,176 ints = 3,800,704 B
    float* agg     = out;                  // agg aliases d_out (safe per-tile)

    const size_t INT_BYTES = 950176u * 4u;                     // 3,800,704
    const size_t FULL_WS   = INT_BYTES + (size_t)N_NODES * D * 2 + 2u * D * D * 2; // ~16.67 MB

    if (ws_size >= FULL_WS) {
        ushort* x_bf = (ushort*)((char*)d_ws + INT_BYTES);
        ushort* Bt   = x_bf + (size_t)N_NODES * D;

        prep_kernel<<<(N_NODES * D / 4 + 255) / 256, 256, 0, stream>>>(x, Wl, Wr, deg, x_bf, Bt);
        hist_kernel<<<(E + 255) / 256, 256, 0, stream>>>(dst, deg, E);
        scanA_kernel<<<SCAN_NBLK, 256, 0, stream>>>(deg, offsets, blocksums);
        scanB_kernel<<<1, 64, 0, stream>>>(blocksums, blockbase, offsets, E);
        scanC_kernel<<<SCAN_NBLK, 256, 0, stream>>>(offsets, blockbase);
        scatter_kernel<<<(E + 255) / 256, 256, 0, stream>>>(src, dst, offsets, cursor, sorted, E);
        aggregate_bf<<<(N_NODES + 7) / 8, 256, 0, stream>>>(x_bf, sorted, offsets, agg);
        gemm_mfma<<<(N_NODES + 127) / 128, 256, 0, stream>>>(agg, x_bf, Bt, b, out);
    } else {
        zero_ints<<<(100032 + 255) / 256, 256, 0, stream>>>(deg, 100032);
        hist_kernel<<<(E + 255) / 256, 256, 0, stream>>>(dst, deg, E);
        scanA_kernel<<<SCAN_NBLK, 256, 0, stream>>>(deg, offsets, blocksums);
        scanB_kernel<<<1, 64, 0, stream>>>(blocksums, blockbase, offsets, E);
        scanC_kernel<<<SCAN_NBLK, 256, 0, stream>>>(offsets, blockbase);
        scatter_kernel<<<(E + 255) / 256, 256, 0, stream>>>(src, dst, offsets, cursor, sorted, E);
        aggregate_kernel<<<(N_NODES + 7) / 8, 256, 0, stream>>>(x, sorted, offsets, agg);
        gemm_fused<<<(N_NODES + 63) / 64, 256, 0, stream>>>(agg, x, Wl, Wr, b, out);
    }
}

// Round 4
// 118.772 us; speedup vs baseline: 2.3336x; 1.2710x over previous
//
#include <hip/hip_runtime.h>

#define N_NODES 50000
#define D 128
#define SCAN_NBLK 49   // ceil(50000/1024)

typedef short bf16x8 __attribute__((ext_vector_type(8)));
typedef float f32x4 __attribute__((ext_vector_type(4)));

__device__ __forceinline__ ushort f2bf(float f) {
    uint u = __float_as_uint(f);
    u += 0x7FFF + ((u >> 16) & 1);     // round-to-nearest-even
    return (ushort)(u >> 16);
}

// ================= prep: zero counters + x->bf16 + W transpose->bf16 ========
__global__ __launch_bounds__(256) void prep_kernel(const float* __restrict__ x,
                                                   const float* __restrict__ Wl,
                                                   const float* __restrict__ Wr,
                                                   int* __restrict__ deg,
                                                   ushort* __restrict__ x_bf,
                                                   ushort* __restrict__ Bt) {
    int i = blockIdx.x * 256 + threadIdx.x;
    if (i < (N_NODES * D) / 4) {
        float4 v = ((const float4*)x)[i];
        ushort4 o;
        o.x = f2bf(v.x); o.y = f2bf(v.y); o.z = f2bf(v.z); o.w = f2bf(v.w);
        ((ushort4*)x_bf)[i] = o;
    }
    if (i < 50016) deg[i] = 0;
    if (i < 2 * D * D) {
        int w = i >> 14;
        int k = (i >> 7) & 127;
        int n = i & 127;
        const float* W = w ? Wr : Wl;
        Bt[w * D * D + n * D + k] = f2bf(W[k * D + n]);
    }
}

// ---------------- histogram + per-edge rank (atomic return value) ----------
__global__ void hist_rank_kernel(const int* __restrict__ dst, int* __restrict__ deg,
                                 int* __restrict__ rank, int E) {
    int e = blockIdx.x * 256 + threadIdx.x;
    if (e < E) rank[e] = atomicAdd(&deg[dst[e]], 1);
}

// ---------------- hierarchical scan ----------------
__global__ __launch_bounds__(256) void scanA_kernel(const int* __restrict__ deg,
                                                    int* __restrict__ offsets,
                                                    int* __restrict__ blocksums) {
    __shared__ int wsums[4];
    __shared__ int wbase[4];
    const int t = threadIdx.x;
    const int lane = t & 63;
    const int wid = t >> 6;
    const int base = blockIdx.x * 1024 + t * 4;

    int v0 = 0, v1 = 0, v2 = 0, v3 = 0;
    if (base + 3 < N_NODES) {
        int4 q = *(const int4*)&deg[base];
        v0 = q.x; v1 = q.y; v2 = q.z; v3 = q.w;
    } else {
        if (base + 0 < N_NODES) v0 = deg[base + 0];
        if (base + 1 < N_NODES) v1 = deg[base + 1];
        if (base + 2 < N_NODES) v2 = deg[base + 2];
        if (base + 3 < N_NODES) v3 = deg[base + 3];
    }
    int tsum = v0 + v1 + v2 + v3;

    int sc = tsum;
    #pragma unroll
    for (int off = 1; off < 64; off <<= 1) {
        int u = __shfl_up(sc, off);
        if (lane >= off) sc += u;
    }
    if (lane == 63) wsums[wid] = sc;
    __syncthreads();
    if (t == 0) {
        int c = 0;
        #pragma unroll
        for (int w = 0; w < 4; ++w) { wbase[w] = c; c += wsums[w]; }
    }
    __syncthreads();

    int excl = wbase[wid] + sc - tsum;
    int o0 = excl, o1 = o0 + v0, o2 = o1 + v1, o3 = o2 + v2;
    if (base + 3 < N_NODES) {
        *(int4*)&offsets[base] = make_int4(o0, o1, o2, o3);
    } else {
        if (base + 0 < N_NODES) offsets[base + 0] = o0;
        if (base + 1 < N_NODES) offsets[base + 1] = o1;
        if (base + 2 < N_NODES) offsets[base + 2] = o2;
        if (base + 3 < N_NODES) offsets[base + 3] = o3;
    }
    if (t == 255) blocksums[blockIdx.x] = excl + tsum;
}

__global__ __launch_bounds__(64) void scanB_kernel(const int* __restrict__ blocksums,
                                                   int* __restrict__ blockbase,
                                                   int* __restrict__ offsets, int E) {
    int t = threadIdx.x;
    int v = (t < SCAN_NBLK) ? blocksums[t] : 0;
    int sc = v;
    #pragma unroll
    for (int off = 1; off < 64; off <<= 1) {
        int u = __shfl_up(sc, off);
        if (t >= off) sc += u;
    }
    if (t < SCAN_NBLK) blockbase[t] = sc - v;
    if (t == 0) offsets[N_NODES] = E;
}

__global__ __launch_bounds__(256) void scanC_kernel(int* __restrict__ offsets,
                                                    const int* __restrict__ blockbase) {
    int b = blockIdx.x;
    int add = blockbase[b];
    if (add == 0) return;
    int base = b * 1024 + threadIdx.x * 4;
    if (base + 3 < N_NODES) {
        int4 q = *(int4*)&offsets[base];
        q.x += add; q.y += add; q.z += add; q.w += add;
        *(int4*)&offsets[base] = q;
    } else {
        if (base + 0 < N_NODES) offsets[base + 0] += add;
        if (base + 1 < N_NODES) offsets[base + 1] += add;
        if (base + 2 < N_NODES) offsets[base + 2] += add;
    }
}

// ---------------- scatter edges into CSR order (no atomics) ----------------
__global__ void scatter_kernel(const int* __restrict__ src, const int* __restrict__ dst,
                               const int* __restrict__ offsets, const int* __restrict__ rank,
                               int* __restrict__ sorted_src, int E) {
    int e = blockIdx.x * 256 + threadIdx.x;
    if (e < E) {
        int d = dst[e];
        sorted_src[offsets[d] + rank[e]] = src[e];
    }
}

// ---------------- per-node mean aggregation (bf16 gather) ----------------
__global__ __launch_bounds__(256) void aggregate_bf(const ushort* __restrict__ x_bf,
                                                    const int* __restrict__ sorted_src,
                                                    const int* __restrict__ offsets,
                                                    float* __restrict__ agg) {
    const int g = threadIdx.x >> 5;
    const int j = threadIdx.x & 31;
    const int node = blockIdx.x * 8 + g;
    if (node >= N_NODES) return;
    const int s = offsets[node];
    const int e = offsets[node + 1];

    float a0 = 0.f, a1 = 0.f, a2 = 0.f, a3 = 0.f;
    int p = s;
    for (; p + 4 <= e; p += 4) {
        int s0 = sorted_src[p], s1 = sorted_src[p + 1];
        int s2 = sorted_src[p + 2], s3 = sorted_src[p + 3];
        uint2 r0 = *(const uint2*)&x_bf[s0 * D + j * 4];
        uint2 r1 = *(const uint2*)&x_bf[s1 * D + j * 4];
        uint2 r2 = *(const uint2*)&x_bf[s2 * D + j * 4];
        uint2 r3 = *(const uint2*)&x_bf[s3 * D + j * 4];
        a0 += __uint_as_float(r0.x << 16) + __uint_as_float(r1.x << 16)
            + __uint_as_float(r2.x << 16) + __uint_as_float(r3.x << 16);
        a1 += __uint_as_float(r0.x & 0xFFFF0000u) + __uint_as_float(r1.x & 0xFFFF0000u)
            + __uint_as_float(r2.x & 0xFFFF0000u) + __uint_as_float(r3.x & 0xFFFF0000u);
        a2 += __uint_as_float(r0.y << 16) + __uint_as_float(r1.y << 16)
            + __uint_as_float(r2.y << 16) + __uint_as_float(r3.y << 16);
        a3 += __uint_as_float(r0.y & 0xFFFF0000u) + __uint_as_float(r1.y & 0xFFFF0000u)
            + __uint_as_float(r2.y & 0xFFFF0000u) + __uint_as_float(r3.y & 0xFFFF0000u);
    }
    for (; p < e; ++p) {
        int s0 = sorted_src[p];
        uint2 r0 = *(const uint2*)&x_bf[s0 * D + j * 4];
        a0 += __uint_as_float(r0.x << 16);
        a1 += __uint_as_float(r0.x & 0xFFFF0000u);
        a2 += __uint_as_float(r0.y << 16);
        a3 += __uint_as_float(r0.y & 0xFFFF0000u);
    }
    const int d = e - s;
    const float sc = (d > 0) ? (1.0f / (float)d) : 0.0f;
    float4 o = make_float4(a0 * sc, a1 * sc, a2 * sc, a3 * sc);
    *(float4*)&agg[node * D + j * 4] = o;
}

// ---------------- MFMA bf16 GEMM: out = relu([agg|x] @ [Wl;Wr] + b) ---------
#define LDA 40   // bf16 units per LDS row (32 data + 8 pad) -> 80B stride
__global__ __launch_bounds__(256) void gemm_mfma(const float* __restrict__ agg,
                                                 const ushort* __restrict__ x_bf,
                                                 const ushort* __restrict__ Bt,
                                                 const float* __restrict__ bias,
                                                 float* __restrict__ out) {
    __shared__ ushort A_s[128 * LDA];
    __shared__ ushort B_s[128 * LDA];

    const int t = threadIdx.x;
    const int n0 = blockIdx.x * 128;
    const int w = t >> 6;
    const int l = t & 63;
    const int lr = l & 15;
    const int kb = l >> 4;

    f32x4 acc[2][8] = {};

    const int srow = t >> 1;
    const int shalf = t & 1;

    for (int ks = 0; ks < 8; ++ks) {
        __syncthreads();
        {
            int gr = n0 + srow;
            if (gr >= N_NODES) gr = N_NODES - 1;
            ushort tmp[16];
            if (ks < 4) {
                const float4* src = (const float4*)(agg + gr * D + ks * 32 + shalf * 16);
                #pragma unroll
                for (int i = 0; i < 4; ++i) {
                    float4 v = src[i];
                    tmp[i * 4 + 0] = f2bf(v.x);
                    tmp[i * 4 + 1] = f2bf(v.y);
                    tmp[i * 4 + 2] = f2bf(v.z);
                    tmp[i * 4 + 3] = f2bf(v.w);
                }
            } else {
                const int4* src = (const int4*)(x_bf + gr * D + (ks - 4) * 32 + shalf * 16);
                ((int4*)tmp)[0] = src[0];
                ((int4*)tmp)[1] = src[1];
            }
            ushort* d = &A_s[srow * LDA + shalf * 16];
            ((int4*)d)[0] = ((int4*)tmp)[0];
            ((int4*)d)[1] = ((int4*)tmp)[1];
        }
        {
            const int4* src = (const int4*)(Bt + (ks >> 2) * D * D + srow * D + (ks & 3) * 32 + shalf * 16);
            ushort* d = &B_s[srow * LDA + shalf * 16];
            ((int4*)d)[0] = src[0];
            ((int4*)d)[1] = src[1];
        }
        __syncthreads();

        bf16x8 af0 = *(bf16x8*)&A_s[(w * 32 + lr) * LDA + kb * 8];
        bf16x8 af1 = *(bf16x8*)&A_s[(w * 32 + 16 + lr) * LDA + kb * 8];
        #pragma unroll
        for (int nf = 0; nf < 8; ++nf) {
            bf16x8 bfr = *(bf16x8*)&B_s[(nf * 16 + lr) * LDA + kb * 8];
            acc[0][nf] = __builtin_amdgcn_mfma_f32_16x16x32_bf16(af0, bfr, acc[0][nf], 0, 0, 0);
            acc[1][nf] = __builtin_amdgcn_mfma_f32_16x16x32_bf16(af1, bfr, acc[1][nf], 0, 0, 0);
        }
    }

    #pragma unroll
    for (int nf = 0; nf < 8; ++nf) {
        const int col = nf * 16 + lr;
        const float bb = bias[col];
        #pragma unroll
        for (int mf = 0; mf < 2; ++mf) {
            #pragma unroll
            for (int i = 0; i < 4; ++i) {
                int row = n0 + w * 32 + mf * 16 + kb * 4 + i;
                if (row < N_NODES)
                    out[row * D + col] = fmaxf(acc[mf][nf][i] + bb, 0.0f);
            }
        }
    }
}

// ================= fallback f32 path (small ws) =============================
__global__ void zero_ints(int* __restrict__ p, int n) {
    int i = blockIdx.x * 256 + threadIdx.x;
    if (i < n) p[i] = 0;
}

__global__ void hist_kernel(const int* __restrict__ dst, int* __restrict__ deg, int E) {
    int e = blockIdx.x * 256 + threadIdx.x;
    if (e < E) atomicAdd(&deg[dst[e]], 1);
}

__global__ void scatter_atomic_kernel(const int* __restrict__ src, const int* __restrict__ dst,
                                      const int* __restrict__ offsets, int* __restrict__ cursor,
                                      int* __restrict__ sorted_src, int E) {
    int e = blockIdx.x * 256 + threadIdx.x;
    if (e < E) {
        int d = dst[e];
        int pos = offsets[d] + atomicAdd(&cursor[d], 1);
        sorted_src[pos] = src[e];
    }
}

__global__ __launch_bounds__(256) void aggregate_kernel(const float* __restrict__ x,
                                                        const int* __restrict__ sorted_src,
                                                        const int* __restrict__ offsets,
                                                        float* __restrict__ agg) {
    const int g = threadIdx.x >> 5;
    const int j = threadIdx.x & 31;
    const int node = blockIdx.x * 8 + g;
    if (node >= N_NODES) return;
    const int s = offsets[node];
    const int e = offsets[node + 1];
    float4 a0 = make_float4(0.f, 0.f, 0.f, 0.f);
    float4 a1 = make_float4(0.f, 0.f, 0.f, 0.f);
    int p = s;
    for (; p + 2 <= e; p += 2) {
        int s0 = sorted_src[p];
        int s1 = sorted_src[p + 1];
        float4 r0 = *(const float4*)&x[s0 * D + j * 4];
        float4 r1 = *(const float4*)&x[s1 * D + j * 4];
        a0.x += r0.x; a0.y += r0.y; a0.z += r0.z; a0.w += r0.w;
        a1.x += r1.x; a1.y += r1.y; a1.z += r1.z; a1.w += r1.w;
    }
    if (p < e) {
        int s0 = sorted_src[p];
        float4 r0 = *(const float4*)&x[s0 * D + j * 4];
        a0.x += r0.x; a0.y += r0.y; a0.z += r0.z; a0.w += r0.w;
    }
    const int d = e - s;
    const float sc = (d > 0) ? (1.0f / (float)d) : 0.0f;
    float4 o;
    o.x = (a0.x + a1.x) * sc;
    o.y = (a0.y + a1.y) * sc;
    o.z = (a0.z + a1.z) * sc;
    o.w = (a0.w + a1.w) * sc;
    *(float4*)&agg[node * D + j * 4] = o;
}

__global__ __launch_bounds__(256) void gemm_fused(const float* __restrict__ agg,
                                                  const float* __restrict__ x,
                                                  const float* __restrict__ Wl,
                                                  const float* __restrict__ Wr,
                                                  const float* __restrict__ bias,
                                                  float* __restrict__ out) {
    __shared__ float As[64][32];
    __shared__ float Xs[64][32];
    __shared__ float Wls[32][128];
    __shared__ float Wrs[32][128];

    const int n0 = blockIdx.x * 64;
    const int t = threadIdx.x;
    const int cg = t & 31;
    const int col0 = cg * 4;
    const int ng = t >> 5;

    float acc[8][4];
    #pragma unroll
    for (int r = 0; r < 8; ++r)
        #pragma unroll
        for (int c = 0; c < 4; ++c) acc[r][c] = 0.0f;

    for (int k0 = 0; k0 < D; k0 += 32) {
        __syncthreads();
        #pragma unroll
        for (int i = 0; i < 4; ++i) {
            int fid = t + i * 256;
            int row = fid >> 5;
            int c4 = fid & 31;
            *(float4*)&Wls[row][c4 * 4] = *(const float4*)&Wl[(k0 + row) * D + c4 * 4];
            *(float4*)&Wrs[row][c4 * 4] = *(const float4*)&Wr[(k0 + row) * D + c4 * 4];
        }
        #pragma unroll
        for (int i = 0; i < 2; ++i) {
            int fid = t + i * 256;
            int row = fid >> 3;
            int m = fid & 7;
            int n = n0 + row;
            int nn = (n < N_NODES) ? n : (N_NODES - 1);
            *(float4*)&As[row][m * 4] = *(const float4*)&agg[nn * D + k0 + m * 4];
            *(float4*)&Xs[row][m * 4] = *(const float4*)&x[nn * D + k0 + m * 4];
        }
        __syncthreads();

        for (int kk = 0; kk < 32; ++kk) {
            const float4 wl = *(const float4*)&Wls[kk][col0];
            const float4 wr = *(const float4*)&Wrs[kk][col0];
            #pragma unroll
            for (int r = 0; r < 8; ++r) {
                float a  = As[ng * 8 + r][kk];
                float xx = Xs[ng * 8 + r][kk];
                acc[r][0] = fmaf(a, wl.x, fmaf(xx, wr.x, acc[r][0]));
                acc[r][1] = fmaf(a, wl.y, fmaf(xx, wr.y, acc[r][1]));
                acc[r][2] = fmaf(a, wl.z, fmaf(xx, wr.z, acc[r][2]));
                acc[r][3] = fmaf(a, wl.w, fmaf(xx, wr.w, acc[r][3]));
            }
        }
    }

    const float4 bb = *(const float4*)&bias[col0];
    #pragma unroll
    for (int r = 0; r < 8; ++r) {
        int n = n0 + ng * 8 + r;
        if (n < N_NODES) {
            float4 o;
            o.x = fmaxf(acc[r][0] + bb.x, 0.0f);
            o.y = fmaxf(acc[r][1] + bb.y, 0.0f);
            o.z = fmaxf(acc[r][2] + bb.z, 0.0f);
            o.w = fmaxf(acc[r][3] + bb.w, 0.0f);
            *(float4*)&out[n * D + col0] = o;
        }
    }
}

// ============================================================================
extern "C" void kernel_launch(void* const* d_in, const int* in_sizes, int n_in,
                              void* d_out, int out_size, void* d_ws, size_t ws_size,
                              hipStream_t stream) {
    const float* x  = (const float*)d_in[0];
    const int*   ei = (const int*)d_in[1];
    const float* Wl = (const float*)d_in[2];
    const float* Wr = (const float*)d_in[3];
    const float* b  = (const float*)d_in[4];
    float* out = (float*)d_out;

    const int E = in_sizes[1] / 2;
    const int* src = ei;
    const int* dst = ei + E;

    // workspace layout (ints first)
    int* deg       = (int*)d_ws;           // 50016
    int* cursor    = deg + 50016;          // 50016 (fallback only)
    int* offsets   = cursor + 50016;       // 50016 (uses 50001)
    int* sorted    = offsets + 50016;      // 800000
    int* blocksums = sorted + 800000;      // 64
    int* blockbase = blocksums + 64;       // 64
    int* rank      = blockbase + 64;       // 800000 (fast path only)
    float* agg     = out;                  // agg aliases d_out (safe per-tile)

    const size_t INT_BYTES = (size_t)(50016 * 3 + 800000 * 2 + 128 + 64) * 4;
    const size_t FULL_WS   = INT_BYTES + (size_t)N_NODES * D * 2 + 2u * D * D * 2;

    if (ws_size >= FULL_WS) {
        ushort* x_bf = (ushort*)((char*)d_ws + INT_BYTES);
        ushort* Bt   = x_bf + (size_t)N_NODES * D;

        prep_kernel<<<(N_NODES * D / 4 + 255) / 256, 256, 0, stream>>>(x, Wl, Wr, deg, x_bf, Bt);
        hist_rank_kernel<<<(E + 255) / 256, 256, 0, stream>>>(dst, deg, rank, E);
        scanA_kernel<<<SCAN_NBLK, 256, 0, stream>>>(deg, offsets, blocksums);
        scanB_kernel<<<1, 64, 0, stream>>>(blocksums, blockbase, offsets, E);
        scanC_kernel<<<SCAN_NBLK, 256, 0, stream>>>(offsets, blockbase);
        scatter_kernel<<<(E + 255) / 256, 256, 0, stream>>>(src, dst, offsets, rank, sorted, E);
        aggregate_bf<<<(N_NODES + 7) / 8, 256, 0, stream>>>(x_bf, sorted, offsets, agg);
        gemm_mfma<<<(N_NODES + 127) / 128, 256, 0, stream>>>(agg, x_bf, Bt, b, out);
    } else {
        zero_ints<<<(100032 + 255) / 256, 256, 0, stream>>>(deg, 100032);
        hist_kernel<<<(E + 255) / 256, 256, 0, stream>>>(dst, deg, E);
        scanA_kernel<<<SCAN_NBLK, 256, 0, stream>>>(deg, offsets, blocksums);
        scanB_kernel<<<1, 64, 0, stream>>>(blocksums, blockbase, offsets, E);
        scanC_kernel<<<SCAN_NBLK, 256, 0, stream>>>(offsets, blockbase);
        scatter_atomic_kernel<<<(E + 255) / 256, 256, 0, stream>>>(src, dst, offsets, cursor, sorted, E);
        aggregate_kernel<<<(N_NODES + 7) / 8, 256, 0, stream>>>(x, sorted, offsets, agg);
        gemm_fused<<<(N_NODES + 63) / 64, 256, 0, stream>>>(agg, x, Wl, Wr, b, out);
    }
}